// Round 27
// baseline (380.623 us; speedup 1.0000x reference)
//
#include <hip/hip_runtime.h>
#include <hip/hip_bf16.h>

typedef __hip_bfloat16 bf16;
typedef __attribute__((ext_vector_type(8))) short bf16x8;
typedef __attribute__((ext_vector_type(4))) float f32x4;

__device__ __forceinline__ void gload_lds16(const void* g, void* s) {
  __builtin_amdgcn_global_load_lds(
      (__attribute__((address_space(1))) void*)(unsigned long long)(uintptr_t)g,
      (__attribute__((address_space(3))) void*)(unsigned int)(uintptr_t)s,
      16, 0, 0);
}

// fast gelu_new: tanh via exp, overflow-safe (|tanh| form), ~10 VALU ops
__device__ __forceinline__ float gelu_new(float x) {
  float u = 0.7978845608028654f * (x + 0.044715f * x * x * x);
  float t = __expf(-2.0f * fabsf(u));
  float th = (1.0f - t) / (1.0f + t);
  th = copysignf(th, u);
  return 0.5f * x * (1.0f + th);
}

__device__ __forceinline__ float bf16bits_to_f32(unsigned short u) {
  return __uint_as_float(((unsigned)u) << 16);
}

// ---------------------------------------------------------------- weight transpose+cast: W[K][N] f32 -> Wt[N][K] bf16
__global__ __launch_bounds__(256) void transpose_cvt(
    const float* __restrict__ W, bf16* __restrict__ Wt, int K, int N) {
  __shared__ float t[64][65];
  const int k0 = blockIdx.y << 6, n0 = blockIdx.x << 6;
  const int tid = threadIdx.x;
#pragma unroll
  for (int i = 0; i < 16; i++) {
    int idx = (i << 8) + tid;
    int r = idx >> 6, c = idx & 63;
    t[r][c] = W[(size_t)(k0 + r) * N + n0 + c];
  }
  __syncthreads();
#pragma unroll
  for (int i = 0; i < 16; i++) {
    int idx = (i << 8) + tid;
    int r = idx >> 6, c = idx & 63;
    Wt[(size_t)(n0 + r) * K + k0 + c] = __float2bfloat16(t[c][r]);
  }
}

// ---------------------------------------------------------------- V transpose: V[bh][s][64] -> Vt[bh][64][s]  (bit-exact)
__global__ __launch_bounds__(256) void vt_k(
    const bf16* __restrict__ V, bf16* __restrict__ Vt) {
  __shared__ __align__(16) short t[64][72];
  const int tid = threadIdx.x;
  const int st = blockIdx.x, bh = blockIdx.y;
  const short* src = (const short*)(V + (size_t)bh * 131072 + (size_t)st * 4096);
#pragma unroll
  for (int i = 0; i < 2; i++) {
    int idx = (i << 8) + tid;
    int r = idx >> 3, c0 = (idx & 7) << 3;
    *reinterpret_cast<bf16x8*>(&t[r][c0]) =
        *reinterpret_cast<const bf16x8*>(src + r * 64 + c0);
  }
  __syncthreads();
  short* dst = (short*)(Vt + (size_t)bh * 131072 + (size_t)st * 64);
#pragma unroll
  for (int i = 0; i < 2; i++) {
    int idx = (i << 8) + tid;
    int hd = idx >> 3, s0 = (idx & 7) << 3;
    bf16x8 o;
#pragma unroll
    for (int j = 0; j < 8; j++) o[j] = t[s0 + j][hd];  // short = short: bit copy
    *reinterpret_cast<bf16x8*>(dst + (size_t)hd * 2048 + s0) = o;
  }
}

// ---------------------------------------------------------------- layernorm, f32 input -> bf16 out (D=1024, block=256)
__global__ __launch_bounds__(256) void ln_f32in(
    const float* __restrict__ x, const float* __restrict__ g,
    const float* __restrict__ b, bf16* __restrict__ out) {
  const int row = blockIdx.x, tid = threadIdx.x;
  const float4 v = reinterpret_cast<const float4*>(x + (size_t)row * 1024)[tid];
  float s1 = v.x + v.y + v.z + v.w;
  float s2 = v.x * v.x + v.y * v.y + v.z * v.z + v.w * v.w;
#pragma unroll
  for (int off = 32; off >= 1; off >>= 1) {
    s1 += __shfl_xor(s1, off);
    s2 += __shfl_xor(s2, off);
  }
  __shared__ float red[8];
  const int wave = tid >> 6;
  if ((tid & 63) == 0) { red[wave * 2] = s1; red[wave * 2 + 1] = s2; }
  __syncthreads();
  s1 = red[0] + red[2] + red[4] + red[6];
  s2 = red[1] + red[3] + red[5] + red[7];
  const float mean = s1 * (1.0f / 1024.0f);
  const float var = s2 * (1.0f / 1024.0f) - mean * mean;
  const float inv = rsqrtf(var + 1e-5f);
  const float4 gv = reinterpret_cast<const float4*>(g)[tid];
  const float4 bv = reinterpret_cast<const float4*>(b)[tid];
  union { bf16 h[4]; uint2 u; } pk;
  pk.h[0] = __float2bfloat16((v.x - mean) * inv * gv.x + bv.x);
  pk.h[1] = __float2bfloat16((v.y - mean) * inv * gv.y + bv.y);
  pk.h[2] = __float2bfloat16((v.z - mean) * inv * gv.z + bv.z);
  pk.h[3] = __float2bfloat16((v.w - mean) * inv * gv.w + bv.w);
  reinterpret_cast<uint2*>(out + (size_t)row * 1024)[tid] = pk.u;
}

// ---------------------------------------------------------------- layernorm, bf16 input -> bf16 out
__global__ __launch_bounds__(256) void ln_bf16in(
    const bf16* __restrict__ x, const float* __restrict__ g,
    const float* __restrict__ b, bf16* __restrict__ out) {
  const int row = blockIdx.x, tid = threadIdx.x;
  union { uint2 u; unsigned short h[4]; } raw;
  raw.u = reinterpret_cast<const uint2*>(x + (size_t)row * 1024)[tid];
  float v[4];
#pragma unroll
  for (int j = 0; j < 4; j++) v[j] = bf16bits_to_f32(raw.h[j]);
  float s1 = v[0] + v[1] + v[2] + v[3];
  float s2 = v[0] * v[0] + v[1] * v[1] + v[2] * v[2] + v[3] * v[3];
#pragma unroll
  for (int off = 32; off >= 1; off >>= 1) {
    s1 += __shfl_xor(s1, off);
    s2 += __shfl_xor(s2, off);
  }
  __shared__ float red[8];
  const int wave = tid >> 6;
  if ((tid & 63) == 0) { red[wave * 2] = s1; red[wave * 2 + 1] = s2; }
  __syncthreads();
  s1 = red[0] + red[2] + red[4] + red[6];
  s2 = red[1] + red[3] + red[5] + red[7];
  const float mean = s1 * (1.0f / 1024.0f);
  const float var = s2 * (1.0f / 1024.0f) - mean * mean;
  const float inv = rsqrtf(var + 1e-5f);
  const float4 gv = reinterpret_cast<const float4*>(g)[tid];
  const float4 bv = reinterpret_cast<const float4*>(b)[tid];
  union { bf16 h[4]; uint2 u; } pk;
#pragma unroll
  for (int j = 0; j < 4; j++) {
    float gj = (&gv.x)[j], bj = (&bv.x)[j];
    pk.h[j] = __float2bfloat16((v[j] - mean) * inv * gj + bj);
  }
  reinterpret_cast<uint2*>(out + (size_t)row * 1024)[tid] = pk.u;
}

// ---------------------------------------------------------------- GEMM: C[M,N] = A[M,K](bf16) * Wt[N,K](bf16)^T + epilogue
// Champion config: BK=64, 2-phase dbuf, T2 both-sides swizzle,
// 2D-chunked XCD remap. EPI=0 folds attn 1/8 scale into Q (pow2: lossless).
template <int EPI>
__global__ __launch_bounds__(256) void gemm_bt(
    const bf16* __restrict__ A, const bf16* __restrict__ W,
    const float* __restrict__ bias, const void* __restrict__ resid,
    void* __restrict__ Cout, int N, int K) {
  __shared__ __align__(16) bf16 As[2][128 * 64];
  __shared__ __align__(16) bf16 Bs[2][128 * 64];
  const int tid = threadIdx.x;
  const int wave = tid >> 6, lane = tid & 63;
  int bx = blockIdx.x, by = blockIdx.y;
  {
    const int gx = gridDim.x, gy = gridDim.y;
    if (((gx & 3) == 0) && ((gy & 1) == 0)) {
      const int orig = by * gx + bx;
      const int cbx = gx >> 2, cby = gy >> 1;   // chunk dims
      const int chunk = orig & 7;               // dispatch round-robin -> XCD
      const int rem = orig >> 3;                // position within chunk
      const int cx = chunk & 3, cy = chunk >> 2;
      bx = cx * cbx + (rem % cbx);              // bx-fastest in chunk
      by = cy * cby + (rem / cbx);
    }
  }
  const int row0 = by << 7, col0 = bx << 7;
  const int wr = (wave >> 1) << 6, wc = (wave & 1) << 6;
  const bf16* Ag = A + (size_t)row0 * K;
  const bf16* Bg = W + (size_t)col0 * K;

  f32x4 acc[4][4];
#pragma unroll
  for (int m = 0; m < 4; m++)
#pragma unroll
    for (int n = 0; n < 4; n++) acc[m][n] = (f32x4){0.f, 0.f, 0.f, 0.f};

  const int lr = lane >> 3;
  const int lc = (((lane & 7) ^ lr) << 3);   // inverse-swizzled source column
  auto stage = [&](int kt, int buf) {
    const bf16* ag = Ag + (kt << 6);
    const bf16* bg = Bg + (kt << 6);
#pragma unroll
    for (int i = 0; i < 4; i++) {
      int br = (i << 5) + (wave << 3);
      gload_lds16(ag + (size_t)(br + lr) * K + lc, As[buf] + br * 64);
      gload_lds16(bg + (size_t)(br + lr) * K + lc, Bs[buf] + br * 64);
    }
  };
  stage(0, 0);
  const int nk = K >> 6;
  const int l7 = lane & 7, lq = lane >> 4, l15 = lane & 15;
  int cur = 0;
  for (int kt = 0; kt < nk; kt++) {
    __syncthreads();
    if (kt + 1 < nk) stage(kt + 1, cur ^ 1);
    const bf16* Asc = As[cur];
    const bf16* Bsc = Bs[cur];
#pragma unroll
    for (int kk = 0; kk < 2; kk++) {
      bf16x8 af[4], bfr[4];
      const int kb = (kk << 2) + lq;
      const int cb = (kb ^ l7) << 3;
#pragma unroll
      for (int m = 0; m < 4; m++)
        af[m] = *reinterpret_cast<const bf16x8*>(Asc + (wr + (m << 4) + l15) * 64 + cb);
#pragma unroll
      for (int n = 0; n < 4; n++)
        bfr[n] = *reinterpret_cast<const bf16x8*>(Bsc + (wc + (n << 4) + l15) * 64 + cb);
#pragma unroll
      for (int m = 0; m < 4; m++)
#pragma unroll
        for (int n = 0; n < 4; n++)
          acc[m][n] = __builtin_amdgcn_mfma_f32_16x16x32_bf16(af[m], bfr[n], acc[m][n], 0, 0, 0);
    }
    cur ^= 1;
  }
  const int rbase = row0 + wr + ((lane >> 4) << 2);
  const int cbase = col0 + wc + (lane & 15);
#pragma unroll
  for (int m = 0; m < 4; m++) {
#pragma unroll
    for (int n = 0; n < 4; n++) {
      const int col = cbase + (n << 4);
      const float bv = bias[col];
#pragma unroll
      for (int j = 0; j < 4; j++) {
        const int row = rbase + (m << 4) + j;
        float v = acc[m][n][j] + bv;
        if constexpr (EPI == 0) {
          int part = col >> 10, rem = col & 1023;
          int hh = rem >> 6, hd = rem & 63;
          int b = row >> 11, sq = row & 2047;
          if (part == 0) v *= 0.125f;   // fold attn scale into Q (pow2: lossless)
          ((bf16*)Cout)[(size_t)part * 8388608 +
                        ((size_t)((b << 4) + hh) * 2048 + sq) * 64 + hd] =
              __float2bfloat16(v);
        } else if constexpr (EPI == 1) {
          v += ((const float*)resid)[(size_t)row * N + col];
          ((bf16*)Cout)[(size_t)row * N + col] = __float2bfloat16(v);
        } else if constexpr (EPI == 2) {
          ((bf16*)Cout)[(size_t)row * N + col] = __float2bfloat16(gelu_new(v));
        } else {
          v += bf16bits_to_f32(((const unsigned short*)resid)[(size_t)row * N + col]);
          ((float*)Cout)[(size_t)row * N + col] = v;
        }
      }
    }
  }
}

// ---------------------------------------------------------------- flash attention, causal, S=2048 HD=64
// Champion version: Q pre-scaled by 1/8, __expf softmax, T13 defer-max,
// dbuf K/V stride-72, 512 threads, pairing {p,15-p}, ones-column PV sum.
__global__ __launch_bounds__(512) void attn_k(
    const bf16* __restrict__ Qb, const bf16* __restrict__ Kb,
    const bf16* __restrict__ Vtg, const float* __restrict__ amask,
    bf16* __restrict__ Aout) {
  __shared__ __align__(16) bf16 Ks[2][64 * 72];
  __shared__ __align__(16) bf16 Vt[2][64 * 72];   // [hd][kv]
  __shared__ __align__(16) bf16 Ps[128][72];
  const int tid = threadIdx.x, wave = tid >> 6, lane = tid & 63;
  const int p = blockIdx.x, bh = blockIdx.y;
  const int b = bh >> 4, h = bh & 15;
  const size_t base = (size_t)bh * 131072;
  const bf16* Kg0 = Kb + base;
  const bf16* Vg0 = Vtg + base;
  const int sr = tid >> 3, scb = (tid & 7) << 3;
  bf16x8 vb1;
#pragma unroll
  for (int j = 0; j < 8; j++) vb1[j] = ((lane & 15) == 0) ? (short)0x3F80 : (short)0;
  int cur = 0;
  const float THR = 8.0f;

  for (int ph = 0; ph < 2; ph++) {
    const int qt = ph ? (15 - p) : p;
    const int q0 = qt << 7;

    bf16x8 qf[2];
    const int qrow = q0 + (wave << 4) + (lane & 15);
#pragma unroll
    for (int kk = 0; kk < 2; kk++)
      qf[kk] = *reinterpret_cast<const bf16x8*>(
          Qb + base + (size_t)qrow * 64 + (kk << 5) + ((lane >> 4) << 3));

    f32x4 oacc[4], osum;
    float mst[4];
#pragma unroll
    for (int n = 0; n < 4; n++) oacc[n] = (f32x4){0.f, 0.f, 0.f, 0.f};
    osum = (f32x4){0.f, 0.f, 0.f, 0.f};
#pragma unroll
    for (int j = 0; j < 4; j++) mst[j] = -INFINITY;

    const int ktmax = (q0 + 127) >> 6;  // inclusive (= 2*qt+1)
    bf16x8 rk, rv;
    rk = *reinterpret_cast<const bf16x8*>(Kg0 + sr * 64 + scb);
    rv = *reinterpret_cast<const bf16x8*>(Vg0 + (size_t)sr * 2048 + scb);
    for (int kt = 0; kt <= ktmax; kt++) {
      *reinterpret_cast<bf16x8*>(Ks[cur] + sr * 72 + scb) = rk;
      *reinterpret_cast<bf16x8*>(Vt[cur] + sr * 72 + scb) = rv;
      __syncthreads();
      if (kt < ktmax) {
        const bf16* Kg = Kg0 + ((size_t)(kt + 1) << 12);
        const bf16* Vg = Vg0 + ((kt + 1) << 6);
        rk = *reinterpret_cast<const bf16x8*>(Kg + sr * 64 + scb);
        rv = *reinterpret_cast<const bf16x8*>(Vg + (size_t)sr * 2048 + scb);
      }

      f32x4 s[4];
#pragma unroll
      for (int n = 0; n < 4; n++) s[n] = (f32x4){0.f, 0.f, 0.f, 0.f};
#pragma unroll
      for (int kk = 0; kk < 2; kk++) {
        const int ko = (kk << 5) + ((lane >> 4) << 3);
#pragma unroll
        for (int n = 0; n < 4; n++) {
          bf16x8 kf = *reinterpret_cast<const bf16x8*>(Ks[cur] + ((n << 4) + (lane & 15)) * 72 + ko);
          s[n] = __builtin_amdgcn_mfma_f32_16x16x32_bf16(qf[kk], kf, s[n], 0, 0, 0);
        }
      }
      float am[4];
#pragma unroll
      for (int n = 0; n < 4; n++)
        am[n] = amask[b * 2048 + (kt << 6) + (n << 4) + (lane & 15)];
      const int rq = q0 + (wave << 4) + ((lane >> 4) << 2);
      if (kt < (qt << 1)) {   // interior: no causal masking possible
#pragma unroll
        for (int n = 0; n < 4; n++)
#pragma unroll
          for (int j = 0; j < 4; j++)
            s[n][j] = s[n][j] + am[n];
      } else {
#pragma unroll
        for (int n = 0; n < 4; n++) {
          const int c = (kt << 6) + (n << 4) + (lane & 15);
#pragma unroll
          for (int j = 0; j < 4; j++) {
            float v = s[n][j] + am[n];
            if (c > rq + j) v = -1e30f;
            s[n][j] = v;
          }
        }
      }
      // ---- online softmax: max-reduce + T13 defer-max rescale
      float rm[4];
      bool ok = true;
#pragma unroll
      for (int j = 0; j < 4; j++) {
        float r = fmaxf(fmaxf(s[0][j], s[1][j]), fmaxf(s[2][j], s[3][j]));
#pragma unroll
        for (int off = 1; off < 16; off <<= 1) r = fmaxf(r, __shfl_xor(r, off));
        rm[j] = r;
        ok = ok && (r <= mst[j] + THR);
      }
      if (!__all(ok)) {
#pragma unroll
        for (int j = 0; j < 4; j++) {
          const float mnew = fmaxf(mst[j], rm[j]);
          const float fac = __expf(mst[j] - mnew);
          mst[j] = mnew;
#pragma unroll
          for (int n = 0; n < 4; n++) oacc[n][j] *= fac;
          osum[j] *= fac;
        }
      }
#pragma unroll
      for (int j = 0; j < 4; j++)
#pragma unroll
        for (int n = 0; n < 4; n++) s[n][j] = __expf(s[n][j] - mst[j]);
      {
        const int prow0 = (wave << 4) + ((lane >> 4) << 2);
#pragma unroll
        for (int n = 0; n < 4; n++)
#pragma unroll
          for (int j = 0; j < 4; j++)
            Ps[prow0 + j][(n << 4) + (lane & 15)] = __float2bfloat16(s[n][j]);
      }
      asm volatile("s_waitcnt lgkmcnt(0)" ::: "memory");
      __builtin_amdgcn_sched_barrier(0);
#pragma unroll
      for (int kk = 0; kk < 2; kk++) {
        const int ko = (kk << 5) + ((lane >> 4) << 3);
        bf16x8 pa = *reinterpret_cast<const bf16x8*>(&Ps[(wave << 4) + (lane & 15)][ko]);
#pragma unroll
        for (int n = 0; n < 4; n++) {
          bf16x8 vb = *reinterpret_cast<const bf16x8*>(Vt[cur] + ((n << 4) + (lane & 15)) * 72 + ko);
          oacc[n] = __builtin_amdgcn_mfma_f32_16x16x32_bf16(pa, vb, oacc[n], 0, 0, 0);
        }
        osum = __builtin_amdgcn_mfma_f32_16x16x32_bf16(pa, vb1, osum, 0, 0, 0);
      }
      cur ^= 1;
    }
    float den[4];
#pragma unroll
    for (int j = 0; j < 4; j++) den[j] = __shfl(osum[j], lane & 48);
#pragma unroll
    for (int n = 0; n < 4; n++)
#pragma unroll
      for (int j = 0; j < 4; j++) {
        const int r = q0 + (wave << 4) + ((lane >> 4) << 2) + j;
        const int c = (h << 6) + (n << 4) + (lane & 15);
        Aout[((size_t)(b * 2048 + r)) * 1024 + c] =
            __float2bfloat16(oacc[n][j] / den[j]);
      }
  }
}

// ---------------------------------------------------------------- launch
extern "C" void kernel_launch(void* const* d_in, const int* in_sizes, int n_in,
                              void* d_out, int out_size, void* d_ws, size_t ws_size,
                              hipStream_t stream) {
  const float* hid   = (const float*)d_in[0];
  const float* amask = (const float*)d_in[1];
  const float* ln1g  = (const float*)d_in[2];
  const float* ln1b  = (const float*)d_in[3];
  const float* Wa    = (const float*)d_in[4];
  const float* ba    = (const float*)d_in[5];
  const float* Wp    = (const float*)d_in[6];
  const float* bp    = (const float*)d_in[7];
  const float* ln2g  = (const float*)d_in[8];
  const float* ln2b  = (const float*)d_in[9];
  const float* Wf    = (const float*)d_in[10];
  const float* bfc   = (const float*)d_in[11];
  const float* Wf2   = (const float*)d_in[12];
  const float* bf2   = (const float*)d_in[13];
  float* out = (float*)d_out;   // reference output dtype is FLOAT32

  if (ws_size < 125829120u) return;  // 120 MB layout (proven to fit)
  char* ws = (char*)d_ws;
  bf16* WtA  = (bf16*)(ws + 0);          //  6 MB
  bf16* WtP  = (bf16*)(ws + 6291456);    //  2 MB
  bf16* WtF  = (bf16*)(ws + 8388608);    //  8 MB
  bf16* WtF2 = (bf16*)(ws + 16777216);   //  8 MB
  bf16* h    = (bf16*)(ws + 25165824);   // 16 MB (reused as h2)
  bf16* qkv  = (bf16*)(ws + 41943040);   // 48 MB
  bf16* a    = (bf16*)(ws + 92274688);   // 16 MB
  bf16* Vt   = (bf16*)(ws + 109051904);  // 16 MB (dead after attn; reused as xmid)
  bf16* xmid = (bf16*)(ws + 109051904);  // 16 MB -> total 120 MB
  bf16* h2  = h;
  bf16* fc1 = qkv;  // overlays qkv+a (both dead): 64 MB

  dim3 blk(256);
  transpose_cvt<<<dim3(48, 16), blk, 0, stream>>>(Wa, WtA, 1024, 3072);
  transpose_cvt<<<dim3(16, 16), blk, 0, stream>>>(Wp, WtP, 1024, 1024);
  transpose_cvt<<<dim3(64, 16), blk, 0, stream>>>(Wf, WtF, 1024, 4096);
  transpose_cvt<<<dim3(16, 64), blk, 0, stream>>>(Wf2, WtF2, 4096, 1024);

  ln_f32in<<<8192, blk, 0, stream>>>(hid, ln1g, ln1b, h);
  gemm_bt<0><<<dim3(24, 64), blk, 0, stream>>>(h, WtA, ba, nullptr, qkv, 3072, 1024);
  vt_k<<<dim3(32, 64), blk, 0, stream>>>(qkv + 16777216, Vt);
  attn_k<<<dim3(8, 64), 512, 0, stream>>>(qkv, qkv + 8388608, Vt, amask, a);
  gemm_bt<1><<<dim3(8, 64), blk, 0, stream>>>(a, WtP, bp, hid, xmid, 1024, 1024);
  ln_bf16in<<<8192, blk, 0, stream>>>(xmid, ln2g, ln2b, h2);
  gemm_bt<2><<<dim3(32, 64), blk, 0, stream>>>(h2, WtF, bfc, nullptr, fc1, 4096, 1024);
  gemm_bt<3><<<dim3(8, 64), blk, 0, stream>>>(fc1, WtF2, bf2, xmid, out, 1024, 4096);
}

// Round 28
// 379.391 us; speedup vs baseline: 1.0032x; 1.0032x over previous
//
#include <hip/hip_runtime.h>
#include <hip/hip_bf16.h>

typedef __hip_bfloat16 bf16;
typedef __attribute__((ext_vector_type(8))) short bf16x8;
typedef __attribute__((ext_vector_type(4))) float f32x4;

__device__ __forceinline__ void gload_lds16(const void* g, void* s) {
  __builtin_amdgcn_global_load_lds(
      (__attribute__((address_space(1))) void*)(unsigned long long)(uintptr_t)g,
      (__attribute__((address_space(3))) void*)(unsigned int)(uintptr_t)s,
      16, 0, 0);
}

// fast gelu_new: tanh via exp, overflow-safe (|tanh| form), ~10 VALU ops
__device__ __forceinline__ float gelu_new(float x) {
  float u = 0.7978845608028654f * (x + 0.044715f * x * x * x);
  float t = __expf(-2.0f * fabsf(u));
  float th = (1.0f - t) / (1.0f + t);
  th = copysignf(th, u);
  return 0.5f * x * (1.0f + th);
}

__device__ __forceinline__ float bf16bits_to_f32(unsigned short u) {
  return __uint_as_float(((unsigned)u) << 16);
}

// ---------------------------------------------------------------- weight transpose+cast: W[K][N] f32 -> Wt[N][K] bf16
__global__ __launch_bounds__(256) void transpose_cvt(
    const float* __restrict__ W, bf16* __restrict__ Wt, int K, int N) {
  __shared__ float t[64][65];
  const int k0 = blockIdx.y << 6, n0 = blockIdx.x << 6;
  const int tid = threadIdx.x;
#pragma unroll
  for (int i = 0; i < 16; i++) {
    int idx = (i << 8) + tid;
    int r = idx >> 6, c = idx & 63;
    t[r][c] = W[(size_t)(k0 + r) * N + n0 + c];
  }
  __syncthreads();
#pragma unroll
  for (int i = 0; i < 16; i++) {
    int idx = (i << 8) + tid;
    int r = idx >> 6, c = idx & 63;
    Wt[(size_t)(n0 + r) * K + k0 + c] = __float2bfloat16(t[c][r]);
  }
}

// ---------------------------------------------------------------- V transpose: V[bh][s][64] -> Vt[bh][64][s]  (bit-exact)
__global__ __launch_bounds__(256) void vt_k(
    const bf16* __restrict__ V, bf16* __restrict__ Vt) {
  __shared__ __align__(16) short t[64][72];
  const int tid = threadIdx.x;
  const int st = blockIdx.x, bh = blockIdx.y;
  const short* src = (const short*)(V + (size_t)bh * 131072 + (size_t)st * 4096);
#pragma unroll
  for (int i = 0; i < 2; i++) {
    int idx = (i << 8) + tid;
    int r = idx >> 3, c0 = (idx & 7) << 3;
    *reinterpret_cast<bf16x8*>(&t[r][c0]) =
        *reinterpret_cast<const bf16x8*>(src + r * 64 + c0);
  }
  __syncthreads();
  short* dst = (short*)(Vt + (size_t)bh * 131072 + (size_t)st * 64);
#pragma unroll
  for (int i = 0; i < 2; i++) {
    int idx = (i << 8) + tid;
    int hd = idx >> 3, s0 = (idx & 7) << 3;
    bf16x8 o;
#pragma unroll
    for (int j = 0; j < 8; j++) o[j] = t[s0 + j][hd];  // short = short: bit copy
    *reinterpret_cast<bf16x8*>(dst + (size_t)hd * 2048 + s0) = o;
  }
}

// ---------------------------------------------------------------- layernorm, f32 input -> bf16 out (D=1024, block=256)
__global__ __launch_bounds__(256) void ln_f32in(
    const float* __restrict__ x, const float* __restrict__ g,
    const float* __restrict__ b, bf16* __restrict__ out) {
  const int row = blockIdx.x, tid = threadIdx.x;
  const float4 v = reinterpret_cast<const float4*>(x + (size_t)row * 1024)[tid];
  float s1 = v.x + v.y + v.z + v.w;
  float s2 = v.x * v.x + v.y * v.y + v.z * v.z + v.w * v.w;
#pragma unroll
  for (int off = 32; off >= 1; off >>= 1) {
    s1 += __shfl_xor(s1, off);
    s2 += __shfl_xor(s2, off);
  }
  __shared__ float red[8];
  const int wave = tid >> 6;
  if ((tid & 63) == 0) { red[wave * 2] = s1; red[wave * 2 + 1] = s2; }
  __syncthreads();
  s1 = red[0] + red[2] + red[4] + red[6];
  s2 = red[1] + red[3] + red[5] + red[7];
  const float mean = s1 * (1.0f / 1024.0f);
  const float var = s2 * (1.0f / 1024.0f) - mean * mean;
  const float inv = rsqrtf(var + 1e-5f);
  const float4 gv = reinterpret_cast<const float4*>(g)[tid];
  const float4 bv = reinterpret_cast<const float4*>(b)[tid];
  union { bf16 h[4]; uint2 u; } pk;
  pk.h[0] = __float2bfloat16((v.x - mean) * inv * gv.x + bv.x);
  pk.h[1] = __float2bfloat16((v.y - mean) * inv * gv.y + bv.y);
  pk.h[2] = __float2bfloat16((v.z - mean) * inv * gv.z + bv.z);
  pk.h[3] = __float2bfloat16((v.w - mean) * inv * gv.w + bv.w);
  reinterpret_cast<uint2*>(out + (size_t)row * 1024)[tid] = pk.u;
}

// ---------------------------------------------------------------- layernorm, bf16 input -> bf16 out
__global__ __launch_bounds__(256) void ln_bf16in(
    const bf16* __restrict__ x, const float* __restrict__ g,
    const float* __restrict__ b, bf16* __restrict__ out) {
  const int row = blockIdx.x, tid = threadIdx.x;
  union { uint2 u; unsigned short h[4]; } raw;
  raw.u = reinterpret_cast<const uint2*>(x + (size_t)row * 1024)[tid];
  float v[4];
#pragma unroll
  for (int j = 0; j < 4; j++) v[j] = bf16bits_to_f32(raw.h[j]);
  float s1 = v[0] + v[1] + v[2] + v[3];
  float s2 = v[0] * v[0] + v[1] * v[1] + v[2] * v[2] + v[3] * v[3];
#pragma unroll
  for (int off = 32; off >= 1; off >>= 1) {
    s1 += __shfl_xor(s1, off);
    s2 += __shfl_xor(s2, off);
  }
  __shared__ float red[8];
  const int wave = tid >> 6;
  if ((tid & 63) == 0) { red[wave * 2] = s1; red[wave * 2 + 1] = s2; }
  __syncthreads();
  s1 = red[0] + red[2] + red[4] + red[6];
  s2 = red[1] + red[3] + red[5] + red[7];
  const float mean = s1 * (1.0f / 1024.0f);
  const float var = s2 * (1.0f / 1024.0f) - mean * mean;
  const float inv = rsqrtf(var + 1e-5f);
  const float4 gv = reinterpret_cast<const float4*>(g)[tid];
  const float4 bv = reinterpret_cast<const float4*>(b)[tid];
  union { bf16 h[4]; uint2 u; } pk;
#pragma unroll
  for (int j = 0; j < 4; j++) {
    float gj = (&gv.x)[j], bj = (&bv.x)[j];
    pk.h[j] = __float2bfloat16((v[j] - mean) * inv * gj + bj);
  }
  reinterpret_cast<uint2*>(out + (size_t)row * 1024)[tid] = pk.u;
}

// ---------------------------------------------------------------- GEMM: C[M,N] = A[M,K](bf16) * Wt[N,K](bf16)^T + epilogue
// Champion config: BK=64, 2-phase dbuf, T2 both-sides swizzle,
// 2D-chunked XCD remap. EPI=0 folds attn 1/8 scale into Q (pow2: lossless).
template <int EPI>
__global__ __launch_bounds__(256) void gemm_bt(
    const bf16* __restrict__ A, const bf16* __restrict__ W,
    const float* __restrict__ bias, const void* __restrict__ resid,
    void* __restrict__ Cout, int N, int K) {
  __shared__ __align__(16) bf16 As[2][128 * 64];
  __shared__ __align__(16) bf16 Bs[2][128 * 64];
  const int tid = threadIdx.x;
  const int wave = tid >> 6, lane = tid & 63;
  int bx = blockIdx.x, by = blockIdx.y;
  {
    const int gx = gridDim.x, gy = gridDim.y;
    if (((gx & 3) == 0) && ((gy & 1) == 0)) {
      const int orig = by * gx + bx;
      const int cbx = gx >> 2, cby = gy >> 1;   // chunk dims
      const int chunk = orig & 7;               // dispatch round-robin -> XCD
      const int rem = orig >> 3;                // position within chunk
      const int cx = chunk & 3, cy = chunk >> 2;
      bx = cx * cbx + (rem % cbx);              // bx-fastest in chunk
      by = cy * cby + (rem / cbx);
    }
  }
  const int row0 = by << 7, col0 = bx << 7;
  const int wr = (wave >> 1) << 6, wc = (wave & 1) << 6;
  const bf16* Ag = A + (size_t)row0 * K;
  const bf16* Bg = W + (size_t)col0 * K;

  f32x4 acc[4][4];
#pragma unroll
  for (int m = 0; m < 4; m++)
#pragma unroll
    for (int n = 0; n < 4; n++) acc[m][n] = (f32x4){0.f, 0.f, 0.f, 0.f};

  const int lr = lane >> 3;
  const int lc = (((lane & 7) ^ lr) << 3);   // inverse-swizzled source column
  auto stage = [&](int kt, int buf) {
    const bf16* ag = Ag + (kt << 6);
    const bf16* bg = Bg + (kt << 6);
#pragma unroll
    for (int i = 0; i < 4; i++) {
      int br = (i << 5) + (wave << 3);
      gload_lds16(ag + (size_t)(br + lr) * K + lc, As[buf] + br * 64);
      gload_lds16(bg + (size_t)(br + lr) * K + lc, Bs[buf] + br * 64);
    }
  };
  stage(0, 0);
  const int nk = K >> 6;
  const int l7 = lane & 7, lq = lane >> 4, l15 = lane & 15;
  int cur = 0;
  for (int kt = 0; kt < nk; kt++) {
    __syncthreads();
    if (kt + 1 < nk) stage(kt + 1, cur ^ 1);
    const bf16* Asc = As[cur];
    const bf16* Bsc = Bs[cur];
#pragma unroll
    for (int kk = 0; kk < 2; kk++) {
      bf16x8 af[4], bfr[4];
      const int kb = (kk << 2) + lq;
      const int cb = (kb ^ l7) << 3;
#pragma unroll
      for (int m = 0; m < 4; m++)
        af[m] = *reinterpret_cast<const bf16x8*>(Asc + (wr + (m << 4) + l15) * 64 + cb);
#pragma unroll
      for (int n = 0; n < 4; n++)
        bfr[n] = *reinterpret_cast<const bf16x8*>(Bsc + (wc + (n << 4) + l15) * 64 + cb);
#pragma unroll
      for (int m = 0; m < 4; m++)
#pragma unroll
        for (int n = 0; n < 4; n++)
          acc[m][n] = __builtin_amdgcn_mfma_f32_16x16x32_bf16(af[m], bfr[n], acc[m][n], 0, 0, 0);
    }
    cur ^= 1;
  }
  const int rbase = row0 + wr + ((lane >> 4) << 2);
  const int cbase = col0 + wc + (lane & 15);
#pragma unroll
  for (int m = 0; m < 4; m++) {
#pragma unroll
    for (int n = 0; n < 4; n++) {
      const int col = cbase + (n << 4);
      const float bv = bias[col];
#pragma unroll
      for (int j = 0; j < 4; j++) {
        const int row = rbase + (m << 4) + j;
        float v = acc[m][n][j] + bv;
        if constexpr (EPI == 0) {
          int part = col >> 10, rem = col & 1023;
          int hh = rem >> 6, hd = rem & 63;
          int b = row >> 11, sq = row & 2047;
          if (part == 0) v *= 0.125f;   // fold attn scale into Q (pow2: lossless)
          ((bf16*)Cout)[(size_t)part * 8388608 +
                        ((size_t)((b << 4) + hh) * 2048 + sq) * 64 + hd] =
              __float2bfloat16(v);
        } else if constexpr (EPI == 1) {
          v += ((const float*)resid)[(size_t)row * N + col];
          ((bf16*)Cout)[(size_t)row * N + col] = __float2bfloat16(v);
        } else if constexpr (EPI == 2) {
          ((bf16*)Cout)[(size_t)row * N + col] = __float2bfloat16(gelu_new(v));
        } else {
          v += bf16bits_to_f32(((const unsigned short*)resid)[(size_t)row * N + col]);
          ((float*)Cout)[(size_t)row * N + col] = v;
        }
      }
    }
  }
}

// ---------------------------------------------------------------- flash attention, causal, S=2048 HD=64
// Champion version: Q pre-scaled by 1/8, __expf softmax, T13 defer-max,
// dbuf K/V stride-72, 512 threads, pairing {p,15-p}, ones-column PV sum.
__global__ __launch_bounds__(512) void attn_k(
    const bf16* __restrict__ Qb, const bf16* __restrict__ Kb,
    const bf16* __restrict__ Vtg, const float* __restrict__ amask,
    bf16* __restrict__ Aout) {
  __shared__ __align__(16) bf16 Ks[2][64 * 72];
  __shared__ __align__(16) bf16 Vt[2][64 * 72];   // [hd][kv]
  __shared__ __align__(16) bf16 Ps[128][72];
  const int tid = threadIdx.x, wave = tid >> 6, lane = tid & 63;
  const int p = blockIdx.x, bh = blockIdx.y;
  const int b = bh >> 4, h = bh & 15;
  const size_t base = (size_t)bh * 131072;
  const bf16* Kg0 = Kb + base;
  const bf16* Vg0 = Vtg + base;
  const int sr = tid >> 3, scb = (tid & 7) << 3;
  bf16x8 vb1;
#pragma unroll
  for (int j = 0; j < 8; j++) vb1[j] = ((lane & 15) == 0) ? (short)0x3F80 : (short)0;
  int cur = 0;
  const float THR = 8.0f;

  for (int ph = 0; ph < 2; ph++) {
    const int qt = ph ? (15 - p) : p;
    const int q0 = qt << 7;

    bf16x8 qf[2];
    const int qrow = q0 + (wave << 4) + (lane & 15);
#pragma unroll
    for (int kk = 0; kk < 2; kk++)
      qf[kk] = *reinterpret_cast<const bf16x8*>(
          Qb + base + (size_t)qrow * 64 + (kk << 5) + ((lane >> 4) << 3));

    f32x4 oacc[4], osum;
    float mst[4];
#pragma unroll
    for (int n = 0; n < 4; n++) oacc[n] = (f32x4){0.f, 0.f, 0.f, 0.f};
    osum = (f32x4){0.f, 0.f, 0.f, 0.f};
#pragma unroll
    for (int j = 0; j < 4; j++) mst[j] = -INFINITY;

    const int ktmax = (q0 + 127) >> 6;  // inclusive (= 2*qt+1)
    bf16x8 rk, rv;
    rk = *reinterpret_cast<const bf16x8*>(Kg0 + sr * 64 + scb);
    rv = *reinterpret_cast<const bf16x8*>(Vg0 + (size_t)sr * 2048 + scb);
    for (int kt = 0; kt <= ktmax; kt++) {
      *reinterpret_cast<bf16x8*>(Ks[cur] + sr * 72 + scb) = rk;
      *reinterpret_cast<bf16x8*>(Vt[cur] + sr * 72 + scb) = rv;
      __syncthreads();
      if (kt < ktmax) {
        const bf16* Kg = Kg0 + ((size_t)(kt + 1) << 12);
        const bf16* Vg = Vg0 + ((kt + 1) << 6);
        rk = *reinterpret_cast<const bf16x8*>(Kg + sr * 64 + scb);
        rv = *reinterpret_cast<const bf16x8*>(Vg + (size_t)sr * 2048 + scb);
      }

      f32x4 s[4];
#pragma unroll
      for (int n = 0; n < 4; n++) s[n] = (f32x4){0.f, 0.f, 0.f, 0.f};
#pragma unroll
      for (int kk = 0; kk < 2; kk++) {
        const int ko = (kk << 5) + ((lane >> 4) << 3);
#pragma unroll
        for (int n = 0; n < 4; n++) {
          bf16x8 kf = *reinterpret_cast<const bf16x8*>(Ks[cur] + ((n << 4) + (lane & 15)) * 72 + ko);
          s[n] = __builtin_amdgcn_mfma_f32_16x16x32_bf16(qf[kk], kf, s[n], 0, 0, 0);
        }
      }
      float am[4];
#pragma unroll
      for (int n = 0; n < 4; n++)
        am[n] = amask[b * 2048 + (kt << 6) + (n << 4) + (lane & 15)];
      const int rq = q0 + (wave << 4) + ((lane >> 4) << 2);
      if (kt < (qt << 1)) {   // interior: no causal masking possible
#pragma unroll
        for (int n = 0; n < 4; n++)
#pragma unroll
          for (int j = 0; j < 4; j++)
            s[n][j] = s[n][j] + am[n];
      } else {
#pragma unroll
        for (int n = 0; n < 4; n++) {
          const int c = (kt << 6) + (n << 4) + (lane & 15);
#pragma unroll
          for (int j = 0; j < 4; j++) {
            float v = s[n][j] + am[n];
            if (c > rq + j) v = -1e30f;
            s[n][j] = v;
          }
        }
      }
      // ---- online softmax: max-reduce + T13 defer-max rescale
      float rm[4];
      bool ok = true;
#pragma unroll
      for (int j = 0; j < 4; j++) {
        float r = fmaxf(fmaxf(s[0][j], s[1][j]), fmaxf(s[2][j], s[3][j]));
#pragma unroll
        for (int off = 1; off < 16; off <<= 1) r = fmaxf(r, __shfl_xor(r, off));
        rm[j] = r;
        ok = ok && (r <= mst[j] + THR);
      }
      if (!__all(ok)) {
#pragma unroll
        for (int j = 0; j < 4; j++) {
          const float mnew = fmaxf(mst[j], rm[j]);
          const float fac = __expf(mst[j] - mnew);
          mst[j] = mnew;
#pragma unroll
          for (int n = 0; n < 4; n++) oacc[n][j] *= fac;
          osum[j] *= fac;
        }
      }
#pragma unroll
      for (int j = 0; j < 4; j++)
#pragma unroll
        for (int n = 0; n < 4; n++) s[n][j] = __expf(s[n][j] - mst[j]);
      {
        const int prow0 = (wave << 4) + ((lane >> 4) << 2);
#pragma unroll
        for (int n = 0; n < 4; n++)
#pragma unroll
          for (int j = 0; j < 4; j++)
            Ps[prow0 + j][(n << 4) + (lane & 15)] = __float2bfloat16(s[n][j]);
      }
      asm volatile("s_waitcnt lgkmcnt(0)" ::: "memory");
      __builtin_amdgcn_sched_barrier(0);
#pragma unroll
      for (int kk = 0; kk < 2; kk++) {
        const int ko = (kk << 5) + ((lane >> 4) << 3);
        bf16x8 pa = *reinterpret_cast<const bf16x8*>(&Ps[(wave << 4) + (lane & 15)][ko]);
#pragma unroll
        for (int n = 0; n < 4; n++) {
          bf16x8 vb = *reinterpret_cast<const bf16x8*>(Vt[cur] + ((n << 4) + (lane & 15)) * 72 + ko);
          oacc[n] = __builtin_amdgcn_mfma_f32_16x16x32_bf16(pa, vb, oacc[n], 0, 0, 0);
        }
        osum = __builtin_amdgcn_mfma_f32_16x16x32_bf16(pa, vb1, osum, 0, 0, 0);
      }
      cur ^= 1;
    }
    float den[4];
#pragma unroll
    for (int j = 0; j < 4; j++) den[j] = __shfl(osum[j], lane & 48);
#pragma unroll
    for (int n = 0; n < 4; n++)
#pragma unroll
      for (int j = 0; j < 4; j++) {
        const int r = q0 + (wave << 4) + ((lane >> 4) << 2) + j;
        const int c = (h << 6) + (n << 4) + (lane & 15);
        Aout[((size_t)(b * 2048 + r)) * 1024 + c] =
            __float2bfloat16(oacc[n][j] / den[j]);
      }
  }
}

// ---------------------------------------------------------------- launch
extern "C" void kernel_launch(void* const* d_in, const int* in_sizes, int n_in,
                              void* d_out, int out_size, void* d_ws, size_t ws_size,
                              hipStream_t stream) {
  const float* hid   = (const float*)d_in[0];
  const float* amask = (const float*)d_in[1];
  const float* ln1g  = (const float*)d_in[2];
  const float* ln1b  = (const float*)d_in[3];
  const float* Wa    = (const float*)d_in[4];
  const float* ba    = (const float*)d_in[5];
  const float* Wp    = (const float*)d_in[6];
  const float* bp    = (const float*)d_in[7];
  const float* ln2g  = (const float*)d_in[8];
  const float* ln2b  = (const float*)d_in[9];
  const float* Wf    = (const float*)d_in[10];
  const float* bfc   = (const float*)d_in[11];
  const float* Wf2   = (const float*)d_in[12];
  const float* bf2   = (const float*)d_in[13];
  float* out = (float*)d_out;   // reference output dtype is FLOAT32

  if (ws_size < 125829120u) return;  // 120 MB layout (proven to fit)
  char* ws = (char*)d_ws;
  bf16* WtA  = (bf16*)(ws + 0);          //  6 MB
  bf16* WtP  = (bf16*)(ws + 6291456);    //  2 MB
  bf16* WtF  = (bf16*)(ws + 8388608);    //  8 MB
  bf16* WtF2 = (bf16*)(ws + 16777216);   //  8 MB
  bf16* h    = (bf16*)(ws + 25165824);   // 16 MB (reused as h2)
  bf16* qkv  = (bf16*)(ws + 41943040);   // 48 MB
  bf16* a    = (bf16*)(ws + 92274688);   // 16 MB
  bf16* Vt   = (bf16*)(ws + 109051904);  // 16 MB (dead after attn; reused as xmid)
  bf16* xmid = (bf16*)(ws + 109051904);  // 16 MB -> total 120 MB
  bf16* h2  = h;
  bf16* fc1 = qkv;  // overlays qkv+a (both dead): 64 MB

  dim3 blk(256);
  transpose_cvt<<<dim3(48, 16), blk, 0, stream>>>(Wa, WtA, 1024, 3072);
  transpose_cvt<<<dim3(16, 16), blk, 0, stream>>>(Wp, WtP, 1024, 1024);
  transpose_cvt<<<dim3(64, 16), blk, 0, stream>>>(Wf, WtF, 1024, 4096);
  transpose_cvt<<<dim3(16, 64), blk, 0, stream>>>(Wf2, WtF2, 4096, 1024);

  ln_f32in<<<8192, blk, 0, stream>>>(hid, ln1g, ln1b, h);
  gemm_bt<0><<<dim3(24, 64), blk, 0, stream>>>(h, WtA, ba, nullptr, qkv, 3072, 1024);
  vt_k<<<dim3(32, 64), blk, 0, stream>>>(qkv + 16777216, Vt);
  attn_k<<<dim3(8, 64), 512, 0, stream>>>(qkv, qkv + 8388608, Vt, amask, a);
  gemm_bt<1><<<dim3(8, 64), blk, 0, stream>>>(a, WtP, bp, hid, xmid, 1024, 1024);
  ln_bf16in<<<8192, blk, 0, stream>>>(xmid, ln2g, ln2b, h2);
  gemm_bt<2><<<dim3(32, 64), blk, 0, stream>>>(h2, WtF, bfc, nullptr, fc1, 4096, 1024);
  gemm_bt<3><<<dim3(8, 64), blk, 0, stream>>>(fc1, WtF2, bf2, xmid, out, 1024, 4096);
}